// Round 13
// baseline (71.145 us; speedup 1.0000x reference)
//
#include <hip/hip_runtime.h>
#include <hip/hip_bf16.h>
#include <math.h>

#define NUM_CLASSES 8192
#define FEAT_DIM    256
#define BATCH       1024
// TEMPERATURE = 0.1 -> logits = dot * 10

typedef long fp8x8;                                  // 8 fp8 in 2 VGPRs
typedef __attribute__((ext_vector_type(4))) float f32x4;

#define GLD16(gp, lp) __builtin_amdgcn_global_load_lds(                       \
    (const __attribute__((address_space(1))) void*)(gp),                      \
    (__attribute__((address_space(3))) void*)(lp), 16, 0, 0)

// ---------------------------------------------------------------------------
// Phase 1: EMA update + fp8 convert, prep-free. One wave per class.
// Blocks 0..31 also zero rowsum.
// ---------------------------------------------------------------------------
__global__ __launch_bounds__(256) void ema_convert_kernel(
    const float* __restrict__ feats, const float* __restrict__ proto,
    const int* __restrict__ labels, unsigned char* __restrict__ P8,
    float* __restrict__ rowsum) {
  __shared__ int lab_s[BATCH];
  const int tid = threadIdx.x;

  ((int4*)lab_s)[tid] = ((const int4*)labels)[tid];   // 256 x 16B = 4 KB
  if (blockIdx.x < 32) rowsum[blockIdx.x * 256 + tid] = 0.0f;
  __syncthreads();

  const int c    = (blockIdx.x << 2) + (tid >> 6);    // class id
  const int lane = tid & 63;

  float4 p = ((const float4*)(proto + (size_t)c * FEAT_DIM))[lane];

  const int4 L0 = ((const int4*)lab_s)[lane * 4 + 0];
  const int4 L1 = ((const int4*)lab_s)[lane * 4 + 1];
  const int4 L2 = ((const int4*)lab_s)[lane * 4 + 2];
  const int4 L3 = ((const int4*)lab_s)[lane * 4 + 3];
  unsigned m = 0;
  m |= (L0.x == c) << 0;  m |= (L0.y == c) << 1;
  m |= (L0.z == c) << 2;  m |= (L0.w == c) << 3;
  m |= (L1.x == c) << 4;  m |= (L1.y == c) << 5;
  m |= (L1.z == c) << 6;  m |= (L1.w == c) << 7;
  m |= (L2.x == c) << 8;  m |= (L2.y == c) << 9;
  m |= (L2.z == c) << 10; m |= (L2.w == c) << 11;
  m |= (L3.x == c) << 12; m |= (L3.y == c) << 13;
  m |= (L3.z == c) << 14; m |= (L3.w == c) << 15;

  unsigned long long wm = __ballot(m != 0);
  while (wm) {                           // wave-uniform (rare path)
    const int src = __ffsll((long long)wm) - 1;
    unsigned mm = __shfl(m, src);
    while (mm) {
      const int j = __ffs(mm) - 1;
      mm &= mm - 1;
      const int t = src * 16 + j;        // ascending t = batch order
      float4 f = ((const float4*)(feats + (size_t)t * FEAT_DIM))[lane];
      float4 r;
      r.x = 0.5f * p.x + 0.5f * f.x;
      r.y = 0.5f * p.y + 0.5f * f.y;
      r.z = 0.5f * p.z + 0.5f * f.z;
      r.w = 0.5f * p.w + 0.5f * f.w;
      float ss = r.x * r.x + r.y * r.y + r.z * r.z + r.w * r.w;
#pragma unroll
      for (int off = 32; off; off >>= 1) ss += __shfl_xor(ss, off);
      float inv = 1.0f / fmaxf(sqrtf(ss), 1e-12f);
      p.x = r.x * inv; p.y = r.y * inv; p.z = r.z * inv; p.w = r.w * inv;
    }
    wm &= wm - 1;
  }

  int v = __builtin_amdgcn_cvt_pk_fp8_f32(p.x, p.y, 0, false);
  v = __builtin_amdgcn_cvt_pk_fp8_f32(p.z, p.w, v, true);
  ((int*)(P8 + (size_t)c * FEAT_DIM))[lane] = v;
}

// ---------------------------------------------------------------------------
// Phase 2: fused fp8 GEMM (P * P^T / T) -> exp -> mask -> row sums.
// A-RESIDENT + THIN-B STAGE-AHEAD pipeline:
//   task = 128 rows (strip I, A resident full-K, 32 KB, staged once/chain)
//        x  64 cols (block J, B 8 KB per BK=128 phase, double-buffered 16 KB)
//   task set: J >= 2I. J in {2I,2I+1} (edge): both (r,c),(c,r) in-task ->
//   row-sums only + diagonal mask; J >= 2I+2: strictly upper -> row-sums +
//   mirrored col-sums. Every unordered pair counted exactly once.
// Chains: fixed I, up to 8 consecutive J; 544 chains = 8 x 68 XCD-bijective.
// Pipeline per phase: SB(next)->other buf; COMPUTE(cur); sync. The stage is
// issued a full compute-phase before its drain (first never-exposed staging
// structure at >=3 blocks/CU). Epilogues write LDS partials; one deferred
// global-atomic flush after the last barrier (R10/R11 lesson).
// LDS: A 32K + Bdbuf 16K + scratch 3K ~= 51 KB -> 3 blocks/CU.
// ---------------------------------------------------------------------------
#define NCHAIN 544

__global__ __launch_bounds__(256, 3) void gemm_rowsum_kernel(
    const unsigned char* __restrict__ P8, float* __restrict__ rowsum) {
  __shared__ __align__(16) char As[128 * 256];        // 32 KB, A full-K
  __shared__ __align__(16) char Bs[2][64 * 128];      // 16 KB, B dbuf
  __shared__ float Lrow[2][128];                      // [wn][row] partials
  __shared__ float Lcol[8][64];                       // [task][col] partials

  // XCD-aware bijective swizzle: 544 = 8 * 68
  const int hw  = blockIdx.x;
  const int bid = (hw & 7) * (NCHAIN / 8) + (hw >> 3);

  // chain decode: I = row strip; chains per I = ceil((64-I)/4)
  int I = 0, rem = bid;
  while (rem >= ((64 - I + 3) >> 2)) { rem -= (64 - I + 3) >> 2; ++I; }
  const int Jstart = 2 * I + rem * 8;
  const int Lc = min(8, 128 - 2 * I - rem * 8);   // tasks in this chain

  const int tid  = threadIdx.x;
  const int wid  = tid >> 6;          // 0..3
  const int lane = tid & 63;
  const int wm   = wid >> 1;          // 0..1 (row half)
  const int wn   = wid & 1;           // 0..1 (col half)
  const int g    = lane >> 4;         // 0..3
  const int rl   = lane & 15;         // 0..15

  // zero scratch (visible after prologue sync)
  ((float*)Lrow)[tid] = 0.0f;
  ((float*)Lcol)[tid] = 0.0f;
  ((float*)Lcol)[tid + 256] = 0.0f;

  // ---- stage A full-K: 32 wave-loads of 1 KB (4 rows x 256 B) ----
  {
    const unsigned char* PA = P8 + (size_t)(I * 128) * FEAT_DIM;
    const int rloc = lane >> 4;        // 0..3 row within load
    const int cph  = lane & 15;        // physical 16B chunk
#pragma unroll
    for (int q = 0; q < 8; ++q) {
      const int Ld = wid * 8 + q;      // 0..31
      const int r  = Ld * 4 + rloc;    // tile row 0..127
      const int cs = cph ^ (r & 15);   // pre-swizzled source chunk (4-bit XOR)
      GLD16(PA + (size_t)r * FEAT_DIM + cs * 16, As + Ld * 1024);
    }
  }

  // ---- B staging: 8 wave-loads of 1 KB (8 rows x 128 B) ----
  const int brloc = lane >> 3;         // 0..7
  const int bcph  = lane & 7;
#define SB(T, KT, BUF)                                                        \
  {                                                                           \
    const unsigned char* PB = P8 + (size_t)((Jstart + (T)) * 64) * FEAT_DIM;  \
    _Pragma("unroll")                                                         \
    for (int q = 0; q < 2; ++q) {                                             \
      const int Ld = wid * 2 + q;      /* 0..7 */                             \
      const int r  = Ld * 8 + brloc;   /* 0..63 */                            \
      const int cs = bcph ^ (r & 7);                                          \
      GLD16(PB + (size_t)r * FEAT_DIM + (KT) * 128 + cs * 16,                 \
            Bs[BUF] + Ld * 1024);                                             \
    }                                                                         \
  }

  SB(0, 0, 0);
  __syncthreads();                     // prologue drain (once per chain)

  f32x4 acc[4][2] = {};

#define COMPUTE(KT, BUF)                                                      \
  {                                                                           \
    _Pragma("unroll")                                                         \
    for (int kk = 0; kk < 4; ++kk) {                                          \
      const int ca = ((KT) * 4 + kk) * 2 + (g >> 1);   /* A chunk 0..15 */    \
      const int cb = kk * 2 + (g >> 1);                /* B chunk 0..7  */    \
      const int ib = (g & 1) * 8;                                             \
      fp8x8 a[4], b[2];                                                       \
      _Pragma("unroll")                                                       \
      for (int mi = 0; mi < 4; ++mi) {                                        \
        const int row = wm * 64 + mi * 16 + rl;                               \
        a[mi] = *(const fp8x8*)(As + row * 256 +                              \
                                ((ca ^ (row & 15)) << 4) + ib);               \
      }                                                                       \
      _Pragma("unroll")                                                       \
      for (int ni = 0; ni < 2; ++ni) {                                        \
        const int row = wn * 32 + ni * 16 + rl;                               \
        b[ni] = *(const fp8x8*)(Bs[BUF] + row * 128 +                         \
                                ((cb ^ (row & 7)) << 4) + ib);                \
      }                                                                       \
      _Pragma("unroll")                                                       \
      for (int mi = 0; mi < 4; ++mi)                                          \
        _Pragma("unroll")                                                     \
        for (int ni = 0; ni < 2; ++ni)                                        \
          acc[mi][ni] = __builtin_amdgcn_mfma_f32_16x16x32_fp8_fp8(           \
              a[mi], b[ni], acc[mi][ni], 0, 0, 0);                            \
    }                                                                         \
  }

  // Epilogue: exp + reduce -> LDS partials. C/D: col=lane&15, row=g*4+reg.
#define EPI(T)                                                                \
  {                                                                           \
    const int Jt = Jstart + (T);                                              \
    const bool edge = ((Jt >> 1) == I);                                       \
    float col[2] = {0.0f, 0.0f};                                              \
    _Pragma("unroll")                                                         \
    for (int mi = 0; mi < 4; ++mi) {                                          \
      _Pragma("unroll")                                                       \
      for (int v = 0; v < 4; ++v) {                                           \
        const int lrow = wm * 64 + mi * 16 + g * 4 + v;                       \
        const int grow = I * 128 + lrow;                                      \
        float rs = 0.0f;                                                      \
        _Pragma("unroll")                                                     \
        for (int ni = 0; ni < 2; ++ni) {                                      \
          const int gcol = Jt * 64 + wn * 32 + ni * 16 + rl;                  \
          float e = __expf(10.0f * acc[mi][ni][v]);                           \
          if (edge && grow == gcol) e = 0.0f;                                 \
          rs += e;                                                            \
          col[ni] += e;                                                       \
        }                                                                     \
        rs += __shfl_xor(rs, 1);                                              \
        rs += __shfl_xor(rs, 2);                                              \
        rs += __shfl_xor(rs, 4);                                              \
        rs += __shfl_xor(rs, 8);                                              \
        if (rl == 0) Lrow[wn][lrow] += rs;   /* same thread owns slot */      \
      }                                                                       \
    }                                                                         \
    _Pragma("unroll")                                                         \
    for (int ni = 0; ni < 2; ++ni) {                                          \
      float cs = col[ni];                                                     \
      cs += __shfl_xor(cs, 16);                                               \
      cs += __shfl_xor(cs, 32);                                               \
      if (g == 0)                                                             \
        atomicAdd(&Lcol[T][wn * 32 + ni * 16 + rl], cs);  /* wm-merge */      \
    }                                                                         \
  }

  // ---- main chain: stage-ahead-by-one-phase, 1 barrier per phase ----------
  for (int t = 0; t < Lc; ++t) {
    SB(t, 1, 1);                       // next phase's B -> buf1 (read @ t-1)
    COMPUTE(0, 0);                     // buf0 staged last phase, drained
    __syncthreads();
    if (t + 1 < Lc) SB(t + 1, 0, 0);   // buf0 reads finished above
    COMPUTE(1, 1);
    EPI(t);
#pragma unroll
    for (int mi = 0; mi < 4; ++mi)
#pragma unroll
      for (int ni = 0; ni < 2; ++ni)
        acc[mi][ni] = (f32x4){0.0f, 0.0f, 0.0f, 0.0f};
    __syncthreads();
  }

  // ---- deferred flush: atomics issued once, never drained ----------------
  if (tid < 128)
    atomicAdd(&rowsum[I * 128 + tid], Lrow[0][tid] + Lrow[1][tid]);
  for (int idx = tid; idx < Lc * 64; idx += 256) {
    const int t = idx >> 6, c = idx & 63;
    const int Jt = Jstart + t;
    if ((Jt >> 1) != I)                // edge tasks: no mirrored col-sums
      atomicAdd(&rowsum[Jt * 64 + c], Lcol[t][c]);
  }
}

// ---------------------------------------------------------------------------
// Phase 3: loss = mean(log(rowsum / 8191))
// ---------------------------------------------------------------------------
__global__ __launch_bounds__(256) void finalize_kernel(
    const float* __restrict__ rowsum, float* __restrict__ out) {
  const int tid = threadIdx.x;
  float s = 0.0f;
  for (int i = tid; i < NUM_CLASSES; i += 256) {
    s += logf(rowsum[i] * (1.0f / (float)(NUM_CLASSES - 1)));
  }
#pragma unroll
  for (int off = 32; off; off >>= 1) s += __shfl_xor(s, off);
  __shared__ float red[4];
  if ((tid & 63) == 0) red[tid >> 6] = s;
  __syncthreads();
  if (tid == 0)
    out[0] = (red[0] + red[1] + red[2] + red[3]) * (1.0f / (float)NUM_CLASSES);
}

// ---------------------------------------------------------------------------
extern "C" void kernel_launch(void* const* d_in, const int* in_sizes, int n_in,
                              void* d_out, int out_size, void* d_ws, size_t ws_size,
                              hipStream_t stream) {
  const float* feats  = (const float*)d_in[0];
  const float* proto  = (const float*)d_in[1];
  const int*   labels = (const int*)d_in[2];
  float*       out    = (float*)d_out;

  char* ws = (char*)d_ws;
  unsigned char* P8 = (unsigned char*)ws;                   // 2 MB fp8 P
  float* rowsum = (float*)(ws + (size_t)NUM_CLASSES * FEAT_DIM);

  ema_convert_kernel<<<NUM_CLASSES / 4, 256, 0, stream>>>(feats, proto, labels,
                                                          P8, rowsum);
  gemm_rowsum_kernel<<<NCHAIN, 256, 0, stream>>>(P8, rowsum);
  finalize_kernel<<<1, 256, 0, stream>>>(rowsum, out);
}

// Round 14
// 69.700 us; speedup vs baseline: 1.0207x; 1.0207x over previous
//
#include <hip/hip_runtime.h>
#include <hip/hip_bf16.h>
#include <math.h>

#define NUM_CLASSES 8192
#define FEAT_DIM    256
#define BATCH       1024
// TEMPERATURE = 0.1 -> logits = dot * 10;  exp(10x) = exp2(14.4269504089 x)

typedef long fp8x8;                                  // 8 fp8 in 2 VGPRs
typedef __attribute__((ext_vector_type(4))) float f32x4;

#define GLD16(gp, lp) __builtin_amdgcn_global_load_lds(                       \
    (const __attribute__((address_space(1))) void*)(gp),                      \
    (__attribute__((address_space(3))) void*)(lp), 16, 0, 0)

// ---------------------------------------------------------------------------
// Phase 1: EMA update + fp8 convert, prep-free. One wave per class.
// Blocks 0..31 also zero rowsum.
// ---------------------------------------------------------------------------
__global__ __launch_bounds__(256) void ema_convert_kernel(
    const float* __restrict__ feats, const float* __restrict__ proto,
    const int* __restrict__ labels, unsigned char* __restrict__ P8,
    float* __restrict__ rowsum) {
  __shared__ int lab_s[BATCH];
  const int tid = threadIdx.x;

  ((int4*)lab_s)[tid] = ((const int4*)labels)[tid];   // 256 x 16B = 4 KB
  if (blockIdx.x < 32) rowsum[blockIdx.x * 256 + tid] = 0.0f;
  __syncthreads();

  const int c    = (blockIdx.x << 2) + (tid >> 6);    // class id
  const int lane = tid & 63;

  float4 p = ((const float4*)(proto + (size_t)c * FEAT_DIM))[lane];

  const int4 L0 = ((const int4*)lab_s)[lane * 4 + 0];
  const int4 L1 = ((const int4*)lab_s)[lane * 4 + 1];
  const int4 L2 = ((const int4*)lab_s)[lane * 4 + 2];
  const int4 L3 = ((const int4*)lab_s)[lane * 4 + 3];
  unsigned m = 0;
  m |= (L0.x == c) << 0;  m |= (L0.y == c) << 1;
  m |= (L0.z == c) << 2;  m |= (L0.w == c) << 3;
  m |= (L1.x == c) << 4;  m |= (L1.y == c) << 5;
  m |= (L1.z == c) << 6;  m |= (L1.w == c) << 7;
  m |= (L2.x == c) << 8;  m |= (L2.y == c) << 9;
  m |= (L2.z == c) << 10; m |= (L2.w == c) << 11;
  m |= (L3.x == c) << 12; m |= (L3.y == c) << 13;
  m |= (L3.z == c) << 14; m |= (L3.w == c) << 15;

  unsigned long long wm = __ballot(m != 0);
  while (wm) {                           // wave-uniform (rare path)
    const int src = __ffsll((long long)wm) - 1;
    unsigned mm = __shfl(m, src);
    while (mm) {
      const int j = __ffs(mm) - 1;
      mm &= mm - 1;
      const int t = src * 16 + j;        // ascending t = batch order
      float4 f = ((const float4*)(feats + (size_t)t * FEAT_DIM))[lane];
      float4 r;
      r.x = 0.5f * p.x + 0.5f * f.x;
      r.y = 0.5f * p.y + 0.5f * f.y;
      r.z = 0.5f * p.z + 0.5f * f.z;
      r.w = 0.5f * p.w + 0.5f * f.w;
      float ss = r.x * r.x + r.y * r.y + r.z * r.z + r.w * r.w;
#pragma unroll
      for (int off = 32; off; off >>= 1) ss += __shfl_xor(ss, off);
      float inv = 1.0f / fmaxf(sqrtf(ss), 1e-12f);
      p.x = r.x * inv; p.y = r.y * inv; p.z = r.z * inv; p.w = r.w * inv;
    }
    wm &= wm - 1;
  }

  int v = __builtin_amdgcn_cvt_pk_fp8_f32(p.x, p.y, 0, false);
  v = __builtin_amdgcn_cvt_pk_fp8_f32(p.z, p.w, v, true);
  ((int*)(P8 + (size_t)c * FEAT_DIM))[lane] = v;
}

// ---------------------------------------------------------------------------
// Phase 2: fused fp8 GEMM (P * P^T / T) -> exp -> mask -> row sums.
// A-IN-REGISTERS + FULL-K B TILES (long-phase design):
//   chain = strip I (128 A-rows, gathered to VGPRs once: 32 regs/lane/wave)
//           x up to 4 J col-blocks of 128. Per task: ONE compute phase of
//           128 MFMAs/wave (~2500 cy) against a full-K 32 KB B tile,
//           double-buffered: SB(t+1) issued at phase start, drained by the
//           phase-end __syncthreads ~3500 cy later -> never exposed.
//   Coverage: task(I,J=I): symmetric block, diag masked, row-sums count
//   both orientations -> no mirror. J>I: row-sums + mirrored col-sums.
// B LDS layout: [row][16B-chunk ^ (row&15)] -> ds_read_b64 conflict-free:
//   16 lanes rl read phys chunk cl^rl (distinct) x distinct bank quads;
//   g-halves split words / chunk parity. No LDS atomics (per-wave col
//   slices merged under the phase barrier). Deferred global-atomic flush.
// LDS: B dbuf 64K + Lrow .5K + Lcolw 2K + Lcolacc 2K = 68.5 KB -> 2 blk/CU.
// Chains: 544 = 8 x 68 bijective XCD swizzle.
// ---------------------------------------------------------------------------
#define NCHAIN 544

__global__ __launch_bounds__(256, 2) void gemm_rowsum_kernel(
    const unsigned char* __restrict__ P8, float* __restrict__ rowsum) {
  __shared__ __align__(16) char Bs[2][128 * 256];     // 64 KB, B dbuf
  __shared__ float Lrow[128];                         // row partials (strip I)
  __shared__ float Lcolw[4][128];                     // per-wave col partials
  __shared__ float Lcolacc[4][128];                   // per-task merged cols

  // XCD-aware bijective swizzle: 544 = 8 * 68
  const int hw  = blockIdx.x;
  const int bid = (hw & 7) * (NCHAIN / 8) + (hw >> 3);

  // chain decode: strip I, J-segment of 4; chains/strip = ceil((64-I)/4)
  int I = 0, rem = bid;
  while (rem >= ((64 - I + 3) >> 2)) { rem -= (64 - I + 3) >> 2; ++I; }
  const int Jstart = I + rem * 4;
  const int Lc = min(4, 64 - Jstart);

  const int tid  = threadIdx.x;
  const int wid  = tid >> 6;          // 0..3
  const int lane = tid & 63;
  const int g    = lane >> 4;         // 0..3
  const int rl   = lane & 15;         // 0..15

  if (tid < 128) Lrow[tid] = 0.0f;

  // ---- A gather into registers: rows I*128 + wid*32 .. +31, full K ------
  // Fragment layout (16x16x32): lane holds A[idx=rl][k=g*8..g*8+7].
  fp8x8 areg[2][8];
  {
    const unsigned char* PA = P8 + (size_t)(I * 128 + wid * 32) * FEAT_DIM;
#pragma unroll
    for (int mi = 0; mi < 2; ++mi)
#pragma unroll
      for (int ks = 0; ks < 8; ++ks)
        areg[mi][ks] = *(const fp8x8*)(PA + (mi * 16 + rl) * FEAT_DIM +
                                       ks * 32 + g * 8);
  }

  // ---- B staging: 32 x 1KB wave-loads (4 rows x 256B), 8/wave -----------
  const int brloc = lane >> 4;          // 0..3 row within load
  const int bcph  = lane & 15;          // physical 16B chunk
#define SB(JT, BUF)                                                           \
  {                                                                           \
    const unsigned char* PB_ = P8 + (size_t)((JT) * 128) * FEAT_DIM;          \
    _Pragma("unroll")                                                         \
    for (int q = 0; q < 8; ++q) {                                             \
      const int Ld = wid * 8 + q;       /* 0..31 */                           \
      const int r  = Ld * 4 + brloc;    /* tile row 0..127 */                 \
      const int cs = bcph ^ (r & 15);   /* pre-swizzled source chunk */       \
      GLD16(PB_ + (size_t)r * FEAT_DIM + cs * 16, &Bs[BUF][Ld * 1024]);       \
    }                                                                         \
  }

  f32x4 acc[2][8] = {};

#define COMPUTE(BUF)                                                          \
  {                                                                           \
    const char* B_ = &Bs[BUF][0];                                             \
    _Pragma("unroll")                                                         \
    for (int ks = 0; ks < 8; ++ks) {                                          \
      fp8x8 b[8];                                                             \
      _Pragma("unroll")                                                       \
      for (int ni = 0; ni < 8; ++ni) {                                        \
        const int row = ni * 16 + rl;                                         \
        const int cl  = ks * 2 + (g >> 1);                                    \
        b[ni] = *(const fp8x8*)(B_ + row * 256 +                              \
                                ((cl ^ (row & 15)) << 4) + (g & 1) * 8);      \
      }                                                                       \
      _Pragma("unroll")                                                       \
      for (int mi = 0; mi < 2; ++mi)                                          \
        _Pragma("unroll")                                                     \
        for (int ni = 0; ni < 8; ++ni)                                        \
          acc[mi][ni] = __builtin_amdgcn_mfma_f32_16x16x32_fp8_fp8(           \
              areg[mi][ks], b[ni], acc[mi][ni], 0, 0, 0);                     \
    }                                                                         \
  }

  // Epilogue: C/D layout col=rl, row=g*4+v. Row partials -> Lrow (same
  // thread owns slot every task: no atomics). Col partials -> Lcolw[wid].
#define EPI(T)                                                                \
  {                                                                           \
    const int  Jt    = Jstart + (T);                                          \
    const bool diagb = (Jt == I);                                             \
    float colp[8] = {0, 0, 0, 0, 0, 0, 0, 0};                                 \
    _Pragma("unroll")                                                         \
    for (int mi = 0; mi < 2; ++mi) {                                          \
      _Pragma("unroll")                                                       \
      for (int v = 0; v < 4; ++v) {                                           \
        const int rstrip = wid * 32 + mi * 16 + g * 4 + v;                    \
        float rs = 0.0f;                                                      \
        _Pragma("unroll")                                                     \
        for (int ni = 0; ni < 8; ++ni) {                                      \
          float e = exp2f(14.4269504089f * acc[mi][ni][v]);                   \
          if (diagb && rstrip == ni * 16 + rl) e = 0.0f;                      \
          rs += e;                                                            \
          colp[ni] += e;                                                      \
        }                                                                     \
        rs += __shfl_xor(rs, 1);                                              \
        rs += __shfl_xor(rs, 2);                                              \
        rs += __shfl_xor(rs, 4);                                              \
        rs += __shfl_xor(rs, 8);                                              \
        if (rl == 0) Lrow[rstrip] += rs;                                      \
      }                                                                       \
    }                                                                         \
    _Pragma("unroll")                                                         \
    for (int ni = 0; ni < 8; ++ni) {                                          \
      float cs = colp[ni];                                                    \
      cs += __shfl_xor(cs, 16);                                               \
      cs += __shfl_xor(cs, 32);                                               \
      if (g == 0) Lcolw[wid][ni * 16 + rl] = cs;                              \
    }                                                                         \
  }

  // ---- main chain: one long phase per task --------------------------------
  SB(Jstart, 0);
  __syncthreads();                      // prologue drain (once per chain)

  int buf = 0;
  for (int t = 0; t < Lc; ++t) {
    if (t + 1 < Lc) SB(Jstart + t + 1, buf ^ 1);  // prefetch next B tile
    COMPUTE(buf);                       // ~2500 cy, hides the prefetch
    EPI(t);                             // ~1000 cy VALU, also hides it
#pragma unroll
    for (int mi = 0; mi < 2; ++mi)
#pragma unroll
      for (int ni = 0; ni < 8; ++ni)
        acc[mi][ni] = (f32x4){0.0f, 0.0f, 0.0f, 0.0f};
    __syncthreads();                    // Lcolw visible; prefetch landed
    if (tid < 128)                      // merge col partials for task t
      Lcolacc[t][tid] = Lcolw[0][tid] + Lcolw[1][tid] +
                        Lcolw[2][tid] + Lcolw[3][tid];
    __syncthreads();                    // merge done before next EPI
    buf ^= 1;
  }

  // ---- deferred flush: atomics issued once, never drained ----------------
  if (tid < 128) atomicAdd(&rowsum[I * 128 + tid], Lrow[tid]);
  for (int idx = tid; idx < Lc * 128; idx += 256) {
    const int t = idx >> 7, c = idx & 127;
    const int Jt = Jstart + t;
    if (Jt != I)                        // diagonal task: no mirrored cols
      atomicAdd(&rowsum[Jt * 128 + c], Lcolacc[t][c]);
  }
}

// ---------------------------------------------------------------------------
// Phase 3: loss = mean(log(rowsum / 8191))
// ---------------------------------------------------------------------------
__global__ __launch_bounds__(256) void finalize_kernel(
    const float* __restrict__ rowsum, float* __restrict__ out) {
  const int tid = threadIdx.x;
  float s = 0.0f;
  for (int i = tid; i < NUM_CLASSES; i += 256) {
    s += logf(rowsum[i] * (1.0f / (float)(NUM_CLASSES - 1)));
  }
#pragma unroll
  for (int off = 32; off; off >>= 1) s += __shfl_xor(s, off);
  __shared__ float red[4];
  if ((tid & 63) == 0) red[tid >> 6] = s;
  __syncthreads();
  if (tid == 0)
    out[0] = (red[0] + red[1] + red[2] + red[3]) * (1.0f / (float)NUM_CLASSES);
}

// ---------------------------------------------------------------------------
extern "C" void kernel_launch(void* const* d_in, const int* in_sizes, int n_in,
                              void* d_out, int out_size, void* d_ws, size_t ws_size,
                              hipStream_t stream) {
  const float* feats  = (const float*)d_in[0];
  const float* proto  = (const float*)d_in[1];
  const int*   labels = (const int*)d_in[2];
  float*       out    = (float*)d_out;

  char* ws = (char*)d_ws;
  unsigned char* P8 = (unsigned char*)ws;                   // 2 MB fp8 P
  float* rowsum = (float*)(ws + (size_t)NUM_CLASSES * FEAT_DIM);

  ema_convert_kernel<<<NUM_CLASSES / 4, 256, 0, stream>>>(feats, proto, labels,
                                                          P8, rowsum);
  gemm_rowsum_kernel<<<NCHAIN, 256, 0, stream>>>(P8, rowsum);
  finalize_kernel<<<1, 256, 0, stream>>>(rowsum, out);
}

// Round 15
// 57.799 us; speedup vs baseline: 1.2309x; 1.2059x over previous
//
#include <hip/hip_runtime.h>
#include <hip/hip_bf16.h>
#include <math.h>

#define NUM_CLASSES 8192
#define FEAT_DIM    256
#define BATCH       1024
// TEMPERATURE = 0.1 -> logits = dot * 10

typedef long fp8x8;                                  // 8 fp8 in 2 VGPRs
typedef __attribute__((ext_vector_type(4))) float f32x4;

#define GLD16(gp, lp) __builtin_amdgcn_global_load_lds(                       \
    (const __attribute__((address_space(1))) void*)(gp),                      \
    (__attribute__((address_space(3))) void*)(lp), 16, 0, 0)

// ---------------------------------------------------------------------------
// Phase 1: EMA update + fp8 convert, prep-free. One wave per class.
// Block loads all 1024 labels to LDS; each lane keeps 16 in registers;
// per-class ordered match iteration via ballot + ffs (ascending t = batch
// order). Blocks 0..31 also zero rowsum.
// ---------------------------------------------------------------------------
__global__ __launch_bounds__(256) void ema_convert_kernel(
    const float* __restrict__ feats, const float* __restrict__ proto,
    const int* __restrict__ labels, unsigned char* __restrict__ P8,
    float* __restrict__ rowsum) {
  __shared__ int lab_s[BATCH];
  const int tid = threadIdx.x;

  ((int4*)lab_s)[tid] = ((const int4*)labels)[tid];   // 256 x 16B = 4 KB
  if (blockIdx.x < 32) rowsum[blockIdx.x * 256 + tid] = 0.0f;
  __syncthreads();

  const int c    = (blockIdx.x << 2) + (tid >> 6);    // class id
  const int lane = tid & 63;

  float4 p = ((const float4*)(proto + (size_t)c * FEAT_DIM))[lane];

  const int4 L0 = ((const int4*)lab_s)[lane * 4 + 0];
  const int4 L1 = ((const int4*)lab_s)[lane * 4 + 1];
  const int4 L2 = ((const int4*)lab_s)[lane * 4 + 2];
  const int4 L3 = ((const int4*)lab_s)[lane * 4 + 3];
  unsigned m = 0;
  m |= (L0.x == c) << 0;  m |= (L0.y == c) << 1;
  m |= (L0.z == c) << 2;  m |= (L0.w == c) << 3;
  m |= (L1.x == c) << 4;  m |= (L1.y == c) << 5;
  m |= (L1.z == c) << 6;  m |= (L1.w == c) << 7;
  m |= (L2.x == c) << 8;  m |= (L2.y == c) << 9;
  m |= (L2.z == c) << 10; m |= (L2.w == c) << 11;
  m |= (L3.x == c) << 12; m |= (L3.y == c) << 13;
  m |= (L3.z == c) << 14; m |= (L3.w == c) << 15;

  unsigned long long wm = __ballot(m != 0);
  while (wm) {                           // wave-uniform (rare path)
    const int src = __ffsll((long long)wm) - 1;
    unsigned mm = __shfl(m, src);
    while (mm) {
      const int j = __ffs(mm) - 1;
      mm &= mm - 1;
      const int t = src * 16 + j;        // ascending t = batch order
      float4 f = ((const float4*)(feats + (size_t)t * FEAT_DIM))[lane];
      float4 r;
      r.x = 0.5f * p.x + 0.5f * f.x;
      r.y = 0.5f * p.y + 0.5f * f.y;
      r.z = 0.5f * p.z + 0.5f * f.z;
      r.w = 0.5f * p.w + 0.5f * f.w;
      float ss = r.x * r.x + r.y * r.y + r.z * r.z + r.w * r.w;
#pragma unroll
      for (int off = 32; off; off >>= 1) ss += __shfl_xor(ss, off);
      float inv = 1.0f / fmaxf(sqrtf(ss), 1e-12f);
      p.x = r.x * inv; p.y = r.y * inv; p.z = r.z * inv; p.w = r.w * inv;
    }
    wm &= wm - 1;
  }

  int v = __builtin_amdgcn_cvt_pk_fp8_f32(p.x, p.y, 0, false);
  v = __builtin_amdgcn_cvt_pk_fp8_f32(p.z, p.w, v, true);
  ((int*)(P8 + (size_t)c * FEAT_DIM))[lane] = v;
}

// ---------------------------------------------------------------------------
// Phase 2: fused fp8 GEMM (P * P^T / T) -> exp -> mask -> row sums.
// R9 configuration = measured optimum across 14 structural variants:
// 128x128 tile, BK=128 fp8, SINGLE 32 KB LDS buffer (4-5 blocks/CU --
// inter-block overlap is the only mechanism that ever hid the stage-drain
// latency at this problem size), 2 barriers per phase, 2-task chains
// (1040 blocks = 8 x 130 bijective XCD swizzle), task-0 epilogue placed
// between STAGE-issue(task1) and its drain barrier. LROW=128B + 3-bit XOR
// chunk swizzle (measured-minimal-conflict layout).
// ---------------------------------------------------------------------------
#define BM 128
#define NB (NUM_CLASSES / BM)           // 64 block-rows
#define NTRI (NB * (NB + 1) / 2)        // 2080 triangular tasks
#define NBLK (NTRI / 2)                 // 1040 blocks, 2 tasks each
#define LROW 128                        // bytes per LDS row (128 fp8)

__global__ __launch_bounds__(256, 4) void gemm_rowsum_kernel(
    const unsigned char* __restrict__ P8, float* __restrict__ rowsum) {
  __shared__ __align__(16) char As[BM * LROW];  // 16 KB
  __shared__ __align__(16) char Bs[BM * LROW];  // 16 KB

  // XCD-aware bijective swizzle: 1040 = 8 * 130
  const int hw  = blockIdx.x;
  const int bid = (hw & 7) * (NBLK / 8) + (hw >> 3);

  // task0 = 2*bid -> (bi0, bj0); task1 = task0+1 (next in row, or next diag)
  int rem = bid * 2, bi0 = 0;
  while (rem >= (NB - bi0)) { rem -= (NB - bi0); ++bi0; }
  const int bj0 = bi0 + rem;
  const int bi1 = (bj0 + 1 < NB) ? bi0 : bi0 + 1;
  const int bj1 = (bj0 + 1 < NB) ? bj0 + 1 : bi0 + 1;

  const int tid  = threadIdx.x;
  const int wid  = tid >> 6;          // 0..3
  const int lane = tid & 63;
  const int wm   = wid >> 1;          // 0..1
  const int wn   = wid & 1;           // 0..1

  f32x4 acc[4][4] = {};

  // staging geometry: 16 x 1KB wave-loads per tile per array (8 rows x 128B
  // each); physical 16B chunk cph holds logical chunk cph ^ rloc.
  const int rloc = lane >> 3;             // 0..7 row within 8-row load
  const int csrc = (lane & 7) ^ rloc;     // pre-swizzled source chunk
  const unsigned char* PA = P8 + (size_t)(bi0 * BM) * FEAT_DIM;
  const unsigned char* PB = P8 + (size_t)(bj0 * BM) * FEAT_DIM;

#define STAGE(kt)                                                             \
  {                                                                           \
    _Pragma("unroll")                                                         \
    for (int q = 0; q < 4; ++q) {                                             \
      const int L = wid * 4 + q;          /* 0..15 */                         \
      const int r = L * 8 + rloc;         /* tile row 0..127 */               \
      const size_t go = (size_t)r * FEAT_DIM + (kt) * 128 + csrc * 16;        \
      GLD16(PA + go, As + L * 1024);                                          \
      GLD16(PB + go, Bs + L * 1024);                                          \
    }                                                                         \
  }

  const int g  = lane >> 4;   // 0..3 (k-subslice within the 32-wide MFMA K)
  const int rl = lane & 15;   // 0..15

  // per-(kk,g) physical-address helper: logical byte = kk*32 + g*8
#define COMPUTE()                                                             \
  {                                                                           \
    _Pragma("unroll")                                                         \
    for (int kk = 0; kk < 4; ++kk) {                                          \
      const int cl = 2 * kk + (g >> 1);   /* logical 16B chunk */             \
      const int ib = (g & 1) * 8;         /* inner byte */                    \
      fp8x8 a[4], b[4];                                                       \
      _Pragma("unroll")                                                       \
      for (int mi = 0; mi < 4; ++mi) {                                        \
        const int row = wm * 64 + mi * 16 + rl;                               \
        a[mi] = *(const fp8x8*)(As + row * LROW + ((cl ^ (row & 7)) << 4) + ib);\
      }                                                                       \
      _Pragma("unroll")                                                       \
      for (int ni = 0; ni < 4; ++ni) {                                        \
        const int row = wn * 64 + ni * 16 + rl;                               \
        b[ni] = *(const fp8x8*)(Bs + row * LROW + ((cl ^ (row & 7)) << 4) + ib);\
      }                                                                       \
      _Pragma("unroll")                                                       \
      for (int mi = 0; mi < 4; ++mi)                                          \
        _Pragma("unroll")                                                     \
        for (int ni = 0; ni < 4; ++ni)                                        \
          acc[mi][ni] = __builtin_amdgcn_mfma_f32_16x16x32_fp8_fp8(           \
              a[mi], b[ni], acc[mi][ni], 0, 0, 0);                            \
    }                                                                         \
  }

  // Epilogue for one task. C/D layout: col=lane&15, row=(lane>>4)*4+reg.
#define EPILOGUE(BI, BJ)                                                      \
  {                                                                           \
    const bool diag = ((BI) == (BJ));                                         \
    float col[4] = {0.0f, 0.0f, 0.0f, 0.0f};                                  \
    _Pragma("unroll")                                                         \
    for (int mi = 0; mi < 4; ++mi) {                                          \
      const int growb = (BI) * BM + wm * 64 + mi * 16 + g * 4;                \
      _Pragma("unroll")                                                       \
      for (int v = 0; v < 4; ++v) {                                           \
        const int grow = growb + v;                                           \
        float rs = 0.0f;                                                      \
        _Pragma("unroll")                                                     \
        for (int ni = 0; ni < 4; ++ni) {                                      \
          const int gcol = (BJ) * BM + wn * 64 + ni * 16 + rl;                \
          float e = __expf(10.0f * acc[mi][ni][v]);                           \
          if (diag && grow == gcol) e = 0.0f;                                 \
          rs += e;                                                            \
          col[ni] += e;                                                       \
        }                                                                     \
        rs += __shfl_xor(rs, 1);                                              \
        rs += __shfl_xor(rs, 2);                                              \
        rs += __shfl_xor(rs, 4);                                              \
        rs += __shfl_xor(rs, 8);                                              \
        if (rl == 0) atomicAdd(&rowsum[grow], rs);                            \
      }                                                                       \
    }                                                                         \
    if (!diag) {                                                              \
      _Pragma("unroll")                                                       \
      for (int ni = 0; ni < 4; ++ni) {                                        \
        float cs = col[ni];                                                   \
        cs += __shfl_xor(cs, 16);                                             \
        cs += __shfl_xor(cs, 32);                                             \
        if (g == 0) {                                                         \
          const int gcol = (BJ) * BM + wn * 64 + ni * 16 + rl;                \
          atomicAdd(&rowsum[gcol], cs);                                       \
        }                                                                     \
      }                                                                       \
    }                                                                         \
  }

  STAGE(0);
  __syncthreads();                       // tile (task0,kt0) landed

#pragma unroll
  for (int p = 0; p < 4; ++p) {          // p = task*2 + kt
    COMPUTE();
    __syncthreads();                     // all LDS reads done before restage
    if (p < 3) {
      if (p == 1) {
        // switch to task1; its kt0 stage is issued, then task0's epilogue
        // (exp/shuffle/atomics) hides the staging drain.
        PA = P8 + (size_t)(bi1 * BM) * FEAT_DIM;
        PB = P8 + (size_t)(bj1 * BM) * FEAT_DIM;
        STAGE(0);
        EPILOGUE(bi0, bj0);
#pragma unroll
        for (int mi = 0; mi < 4; ++mi)
#pragma unroll
          for (int ni = 0; ni < 4; ++ni)
            acc[mi][ni] = (f32x4){0.0f, 0.0f, 0.0f, 0.0f};
      } else {
        STAGE(1);                        // p==0 -> t0k1; p==2 -> t1k1
      }
      __syncthreads();                   // staged tile landed
    }
  }

  EPILOGUE(bi1, bj1);
}

// ---------------------------------------------------------------------------
// Phase 3: loss = mean(log(rowsum / 8191))
// ---------------------------------------------------------------------------
__global__ __launch_bounds__(256) void finalize_kernel(
    const float* __restrict__ rowsum, float* __restrict__ out) {
  const int tid = threadIdx.x;
  float s = 0.0f;
  for (int i = tid; i < NUM_CLASSES; i += 256) {
    s += logf(rowsum[i] * (1.0f / (float)(NUM_CLASSES - 1)));
  }
#pragma unroll
  for (int off = 32; off; off >>= 1) s += __shfl_xor(s, off);
  __shared__ float red[4];
  if ((tid & 63) == 0) red[tid >> 6] = s;
  __syncthreads();
  if (tid == 0)
    out[0] = (red[0] + red[1] + red[2] + red[3]) * (1.0f / (float)NUM_CLASSES);
}

// ---------------------------------------------------------------------------
extern "C" void kernel_launch(void* const* d_in, const int* in_sizes, int n_in,
                              void* d_out, int out_size, void* d_ws, size_t ws_size,
                              hipStream_t stream) {
  const float* feats  = (const float*)d_in[0];
  const float* proto  = (const float*)d_in[1];
  const int*   labels = (const int*)d_in[2];
  float*       out    = (float*)d_out;

  char* ws = (char*)d_ws;
  unsigned char* P8 = (unsigned char*)ws;                   // 2 MB fp8 P
  float* rowsum = (float*)(ws + (size_t)NUM_CLASSES * FEAT_DIM);

  ema_convert_kernel<<<NUM_CLASSES / 4, 256, 0, stream>>>(feats, proto, labels,
                                                          P8, rowsum);
  gemm_rowsum_kernel<<<NBLK, 256, 0, stream>>>(P8, rowsum);
  finalize_kernel<<<1, 256, 0, stream>>>(rowsum, out);
}